// Round 3
// baseline (1229.726 us; speedup 1.0000x reference)
//
#include <hip/hip_runtime.h>

#define TT 2048
#define BB 64
#define HH 256   // EMB == HID == 256

typedef _Float16 half2_t __attribute__((ext_vector_type(2)));
typedef _Float16 half8_t __attribute__((ext_vector_type(8)));
typedef float f32x4 __attribute__((ext_vector_type(4)));

static __device__ __forceinline__ float fdot2(half2_t a, half2_t b, float c) {
#if __has_builtin(__builtin_amdgcn_fdot2)
  return __builtin_amdgcn_fdot2(a, b, c, false);   // v_dot2_f32_f16, f32 accum
#else
  return c + (float)a[0] * (float)b[0] + (float)a[1] * (float)b[1];
#endif
}
static __device__ __forceinline__ half2_t bch2(unsigned int u) {
  return __builtin_bit_cast(half2_t, u);
}
template <int PAT>
static __device__ __forceinline__ float swz_add(float x) {
  // x += value from lane ((l & 0x1F) ^ xor_mask) within the 32-lane group
  const int yi = __builtin_amdgcn_ds_swizzle(__builtin_bit_cast(int, x), PAT);
  return x + __builtin_bit_cast(float, yi);
}

// ---------------------------------------------------------------------------
// prep: transpose + fp16-convert W_ih and W_hh into [N][K] row-major.
// ---------------------------------------------------------------------------
__global__ void prep_kernel(const float* __restrict__ Wih, const float* __restrict__ Whh,
                            _Float16* __restrict__ WihT, _Float16* __restrict__ WhhT) {
  const int n = blockIdx.x;   // output column
  const int k = threadIdx.x;  // input row
  WihT[n * HH + k] = (_Float16)Wih[k * HH + n];
  WhhT[n * HH + k] = (_Float16)Whh[k * HH + n];
}

// ---------------------------------------------------------------------------
// Part A: U[t][b][n] = (emb[source[b][t]] @ W_ih)[n] + b_ih[n] + b_hh[n], fp16.
// (unchanged — verified correct; scan dominates runtime)
// ---------------------------------------------------------------------------
__global__ __launch_bounds__(256, 2) void embed_gemm_kernel(
    const int* __restrict__ source, const float* __restrict__ emb,
    const _Float16* __restrict__ WihT, const float* __restrict__ b_ih,
    const float* __restrict__ b_hh, _Float16* __restrict__ U) {
  const int t = blockIdx.x;
  const int nbase = blockIdx.y * 64;
  __shared__ __align__(16) _Float16 Bs[64][280];

  const int tid = threadIdx.x;
  for (int c = tid; c < 64 * 32; c += 256) {
    const int n = c >> 5;
    const int ko = (c & 31) * 8;
    *(half8_t*)&Bs[n][ko] = *(const half8_t*)(WihT + (size_t)(nbase + n) * HH + ko);
  }
  __syncthreads();

  const int lane = tid & 63;
  const int wave = tid >> 6;
  const int row16 = lane & 15;
  const int quad = lane >> 4;
  const int b = wave * 16 + row16;              // A-fragment row = batch
  const int src = source[b * TT + t];           // source is [B][T]
  const float* arow = emb + (size_t)src * HH + quad * 8;

  f32x4 acc[4];
#pragma unroll
  for (int ct = 0; ct < 4; ++ct) acc[ct] = (f32x4){0.f, 0.f, 0.f, 0.f};

#pragma unroll
  for (int kt = 0; kt < 8; ++kt) {
    const float4 x0 = *(const float4*)(arow + kt * 32);
    const float4 x1 = *(const float4*)(arow + kt * 32 + 4);
    half8_t af;
    af[0] = (_Float16)x0.x; af[1] = (_Float16)x0.y;
    af[2] = (_Float16)x0.z; af[3] = (_Float16)x0.w;
    af[4] = (_Float16)x1.x; af[5] = (_Float16)x1.y;
    af[6] = (_Float16)x1.z; af[7] = (_Float16)x1.w;
#pragma unroll
    for (int ct = 0; ct < 4; ++ct) {
      const half8_t bf = *(const half8_t*)&Bs[ct * 16 + row16][quad * 8 + kt * 32];
      acc[ct] = __builtin_amdgcn_mfma_f32_16x16x32_f16(af, bf, acc[ct], 0, 0, 0);
    }
  }

#pragma unroll
  for (int ct = 0; ct < 4; ++ct) {
    const int nn = nbase + ct * 16 + row16;     // C col = lane&15
    const float bias = b_ih[nn] + b_hh[nn];
#pragma unroll
    for (int r = 0; r < 4; ++r) {
      const int bb = wave * 16 + quad * 4 + r;  // C row = quad*4 + reg
      U[((size_t)t * BB + bb) * HH + nn] = (_Float16)(acc[ct][r] + bias);
    }
  }
}

// ---------------------------------------------------------------------------
// Part B: recurrence via VALU v_dot2_f32_f16 (R12 — 8-wave in-wave-reduce).
//   R10/R11 post-mortem: WRITE_SIZE=64KB (output only) -> no scratch spill;
//   VALU instrs/step ~293 vs ~160 expected -> weights lived in the AGPR half
//   of the unified RF with a shuttle op per use. 128 quad-aligned half8 live
//   ranges exceeded whatever budget the allocator actually honors (VGPR=132).
//   Fix: shrink demand below any plausible budget and drop tuple constraints:
//     * 8 waves (512 thr, 2/SIMD). Lane (w, ng=l>>2, kp=l&3) owns outputs
//       n in {32w+2ng, 32w+2ng+1} over k-slice [64kp,64kp+64):
//       weights = 64 single-dword half2 regs; hv = 32 regs; total ~135.
//     * k-reduce IN-WAVE: ds_swizzle butterfly xor1+xor2 (4 swizzle + 4 add)
//       replaces the pbuf write->barrier->read round-trip entirely.
//     * h double-buffered, kp-slices padded to 144B stride (banks 4kp..) ->
//       conflict-free 4-address broadcast ds_read_b128.
//     * still ONE raw lgkmcnt(0);s_barrier per step; u prefetch unchanged
//       (vmcnt never drained in-loop). 2 waves/SIMD hide LDS latency.
//   Arithmetic: per-SIMD issue ~ 2x(64 dot + 8 read + ~25 misc) ~ 390 cy
//   -> step ~430-480 cy vs 1103 now.
// ---------------------------------------------------------------------------
__global__ __launch_bounds__(512)
__attribute__((amdgpu_waves_per_eu(2, 2)))
void rnn_scan_kernel(
    const _Float16* __restrict__ U, const _Float16* __restrict__ WhhT,
    float* __restrict__ out) {
  const int b = blockIdx.x;
  const int tid = threadIdx.x;   // 0..511
  const int w = tid >> 6;        // wave 0..7: owns n in [32w, 32w+32)
  const int l = tid & 63;
  const int kp = l & 3;          // k-part: k in [64kp, 64kp+64)
  const int ng = l >> 2;         // 0..15
  const int n0 = 32 * w + 2 * ng;        // this lane's two outputs: n0, n0+1
  const int nfin = n0 + (kp & 1);        // output this lane finalizes (kp<2)

  // h ping-pong: 4 k-slices x 72 halfs (144B stride -> kp slices start on
  // distinct bank quads -> the 4-address broadcast read is conflict-free).
  __shared__ __align__(16) _Float16 hbuf[2][4][72];

  // ---- weights: w2[j][i] = WhhT[n0+j][64kp + 2i, 64kp + 2i + 1] ----
  // 64 individually-allocable dword values (no quad-tuple constraints).
  half2_t w2[2][32];
#pragma unroll
  for (int j = 0; j < 2; ++j) {
    const uint4* wp = (const uint4*)(WhhT + (size_t)(n0 + j) * HH + 64 * kp);
#pragma unroll
    for (int r = 0; r < 8; ++r) {
      const uint4 q = wp[r];
      w2[j][4 * r + 0] = bch2(q.x); w2[j][4 * r + 1] = bch2(q.y);
      w2[j][4 * r + 2] = bch2(q.z); w2[j][4 * r + 3] = bch2(q.w);
    }
  }
  // Keep them arch-VGPR-resident: single-dword "+v" pins (easy constraints).
  asm volatile("" : "+v"(w2[0][0]), "+v"(w2[0][1]), "+v"(w2[0][2]), "+v"(w2[0][3]),
                    "+v"(w2[0][4]), "+v"(w2[0][5]), "+v"(w2[0][6]), "+v"(w2[0][7]),
                    "+v"(w2[0][8]), "+v"(w2[0][9]), "+v"(w2[0][10]), "+v"(w2[0][11]),
                    "+v"(w2[0][12]), "+v"(w2[0][13]), "+v"(w2[0][14]), "+v"(w2[0][15]));
  asm volatile("" : "+v"(w2[0][16]), "+v"(w2[0][17]), "+v"(w2[0][18]), "+v"(w2[0][19]),
                    "+v"(w2[0][20]), "+v"(w2[0][21]), "+v"(w2[0][22]), "+v"(w2[0][23]),
                    "+v"(w2[0][24]), "+v"(w2[0][25]), "+v"(w2[0][26]), "+v"(w2[0][27]),
                    "+v"(w2[0][28]), "+v"(w2[0][29]), "+v"(w2[0][30]), "+v"(w2[0][31]));
  asm volatile("" : "+v"(w2[1][0]), "+v"(w2[1][1]), "+v"(w2[1][2]), "+v"(w2[1][3]),
                    "+v"(w2[1][4]), "+v"(w2[1][5]), "+v"(w2[1][6]), "+v"(w2[1][7]),
                    "+v"(w2[1][8]), "+v"(w2[1][9]), "+v"(w2[1][10]), "+v"(w2[1][11]),
                    "+v"(w2[1][12]), "+v"(w2[1][13]), "+v"(w2[1][14]), "+v"(w2[1][15]));
  asm volatile("" : "+v"(w2[1][16]), "+v"(w2[1][17]), "+v"(w2[1][18]), "+v"(w2[1][19]),
                    "+v"(w2[1][20]), "+v"(w2[1][21]), "+v"(w2[1][22]), "+v"(w2[1][23]),
                    "+v"(w2[1][24]), "+v"(w2[1][25]), "+v"(w2[1][26]), "+v"(w2[1][27]),
                    "+v"(w2[1][28]), "+v"(w2[1][29]), "+v"(w2[1][30]), "+v"(w2[1][31]));

  // h0 = 0 (zero both buffers)
  for (int i = tid; i < 2 * 4 * 72; i += 512) ((_Float16*)hbuf)[i] = (_Float16)0.f;

  // u stream: lane finalizes n = nfin (kp>=2 lanes load duplicates; uniform).
  const _Float16* Up = U + (size_t)b * HH + nfin;  // step stride = BB*HH halfs
  _Float16 uc[8], un[8];
#pragma unroll
  for (int s = 0; s < 8; ++s) uc[s] = Up[(size_t)s * (BB * HH)];

  float hn = 0.f;
  __syncthreads();  // once, outside the loop (vmcnt drain here is harmless)

  for (int tc = 0; tc < TT; tc += 8) {
    // Issue next-chunk u-loads; raw barriers below never drain vmcnt.
    const int tn = (tc + 8) & (TT - 1);
#pragma unroll
    for (int s = 0; s < 8; ++s) un[s] = Up[(size_t)(tn + s) * (BB * HH)];

#pragma unroll
    for (int s = 0; s < 8; ++s) {
      const int t = tc + s;

      // ---- read own k-slice of h: 8 x ds_read_b128, 4-addr broadcast ----
      const uint4* hp = (const uint4*)(&hbuf[t & 1][kp][0]);
      half2_t h2[32];
#pragma unroll
      for (int r = 0; r < 8; ++r) {
        const uint4 q = hp[r];
        h2[4 * r + 0] = bch2(q.x); h2[4 * r + 1] = bch2(q.y);
        h2[4 * r + 2] = bch2(q.z); h2[4 * r + 3] = bch2(q.w);
      }

      // ---- 64 fdot2, 4 independent chains (2 outputs x even/odd) ----
      float a00 = 0.f, a01 = 0.f, a10 = 0.f, a11 = 0.f;
#pragma unroll
      for (int i = 0; i < 32; i += 2) {
        a00 = fdot2(h2[i],     w2[0][i],     a00);
        a10 = fdot2(h2[i],     w2[1][i],     a10);
        a01 = fdot2(h2[i + 1], w2[0][i + 1], a01);
        a11 = fdot2(h2[i + 1], w2[1][i + 1], a11);
      }
      float a0 = a00 + a01;
      float a1 = a10 + a11;

      // ---- in-wave k-reduce over kp: butterfly xor1 then xor2 ----
      a0 = swz_add<0x041F>(a0);  // += lane^1
      a1 = swz_add<0x041F>(a1);
      a0 = swz_add<0x081F>(a0);  // += lane^2  -> full sum in all 4 kp lanes
      a1 = swz_add<0x081F>(a1);

      // ---- finalize n = nfin (computed uniformly; written by kp<2) ----
      const float y = (kp & 1) ? a1 : a0;
      const float a = (float)uc[s] + y;
      // tanh(a) = 1 - 2/(exp(2a)+1)
      const float e = __builtin_amdgcn_exp2f(a * 2.885390081777927f);  // 2*log2(e)
      hn = 1.f - 2.f * __builtin_amdgcn_rcpf(e + 1.f);
      if (kp < 2) hbuf[(t + 1) & 1][nfin >> 6][nfin & 63] = (_Float16)hn;

      // ONE raw barrier/step: drain own LDS ops only; vmcnt untouched.
      asm volatile("s_waitcnt lgkmcnt(0)\n\ts_barrier" ::: "memory");
    }
#pragma unroll
    for (int s = 0; s < 8; ++s) uc[s] = un[s];
  }
  if (kp < 2) out[(size_t)b * HH + nfin] = hn;
}

// ---------------------------------------------------------------------------
extern "C" void kernel_launch(void* const* d_in, const int* in_sizes, int n_in,
                              void* d_out, int out_size, void* d_ws, size_t ws_size,
                              hipStream_t stream) {
  const int*   source = (const int*)d_in[0];
  const float* emb    = (const float*)d_in[1];
  const float* Wih    = (const float*)d_in[2];
  const float* Whh    = (const float*)d_in[3];
  const float* bih    = (const float*)d_in[4];
  const float* bhh    = (const float*)d_in[5];
  float* out = (float*)d_out;

  char* ws = (char*)d_ws;
  _Float16* U    = (_Float16*)ws;                    // 2048*64*256*2 = 67,108,864 B
  _Float16* WihT = (_Float16*)(ws + 67108864);       // 131,072 B
  _Float16* WhhT = (_Float16*)(ws + 67239936);       // 131,072 B (total ~67.4 MB)

  prep_kernel<<<dim3(256), dim3(256), 0, stream>>>(Wih, Whh, WihT, WhhT);
  embed_gemm_kernel<<<dim3(TT, 4), dim3(256), 0, stream>>>(source, emb, WihT, bih, bhh, U);
  rnn_scan_kernel<<<dim3(BB), dim3(512), 0, stream>>>(U, WhhT, out);
}

// Round 4
// 1220.042 us; speedup vs baseline: 1.0079x; 1.0079x over previous
//
#include <hip/hip_runtime.h>

#define TT 2048
#define BB 64
#define HH 256   // EMB == HID == 256

typedef _Float16 half2_t __attribute__((ext_vector_type(2)));
typedef _Float16 half8_t __attribute__((ext_vector_type(8)));
typedef float f32x4 __attribute__((ext_vector_type(4)));

static __device__ __forceinline__ float fdot2(half2_t a, half2_t b, float c) {
#if __has_builtin(__builtin_amdgcn_fdot2)
  return __builtin_amdgcn_fdot2(a, b, c, false);   // v_dot2_f32_f16, f32 accum
#else
  return c + (float)a[0] * (float)b[0] + (float)a[1] * (float)b[1];
#endif
}

// ---------------------------------------------------------------------------
// prep: transpose + fp16-convert W_ih and W_hh into [N][K] row-major.
// ---------------------------------------------------------------------------
__global__ void prep_kernel(const float* __restrict__ Wih, const float* __restrict__ Whh,
                            _Float16* __restrict__ WihT, _Float16* __restrict__ WhhT) {
  const int n = blockIdx.x;   // output column
  const int k = threadIdx.x;  // input row
  WihT[n * HH + k] = (_Float16)Wih[k * HH + n];
  WhhT[n * HH + k] = (_Float16)Whh[k * HH + n];
}

// ---------------------------------------------------------------------------
// Part A: U[t][b][n] = (emb[source[b][t]] @ W_ih)[n] + b_ih[n] + b_hh[n], fp16.
// (unchanged — verified correct; scan dominates runtime)
// ---------------------------------------------------------------------------
__global__ __launch_bounds__(256, 2) void embed_gemm_kernel(
    const int* __restrict__ source, const float* __restrict__ emb,
    const _Float16* __restrict__ WihT, const float* __restrict__ b_ih,
    const float* __restrict__ b_hh, _Float16* __restrict__ U) {
  const int t = blockIdx.x;
  const int nbase = blockIdx.y * 64;
  __shared__ __align__(16) _Float16 Bs[64][280];

  const int tid = threadIdx.x;
  for (int c = tid; c < 64 * 32; c += 256) {
    const int n = c >> 5;
    const int ko = (c & 31) * 8;
    *(half8_t*)&Bs[n][ko] = *(const half8_t*)(WihT + (size_t)(nbase + n) * HH + ko);
  }
  __syncthreads();

  const int lane = tid & 63;
  const int wave = tid >> 6;
  const int row16 = lane & 15;
  const int quad = lane >> 4;
  const int b = wave * 16 + row16;              // A-fragment row = batch
  const int src = source[b * TT + t];           // source is [B][T]
  const float* arow = emb + (size_t)src * HH + quad * 8;

  f32x4 acc[4];
#pragma unroll
  for (int ct = 0; ct < 4; ++ct) acc[ct] = (f32x4){0.f, 0.f, 0.f, 0.f};

#pragma unroll
  for (int kt = 0; kt < 8; ++kt) {
    const float4 x0 = *(const float4*)(arow + kt * 32);
    const float4 x1 = *(const float4*)(arow + kt * 32 + 4);
    half8_t af;
    af[0] = (_Float16)x0.x; af[1] = (_Float16)x0.y;
    af[2] = (_Float16)x0.z; af[3] = (_Float16)x0.w;
    af[4] = (_Float16)x1.x; af[5] = (_Float16)x1.y;
    af[6] = (_Float16)x1.z; af[7] = (_Float16)x1.w;
#pragma unroll
    for (int ct = 0; ct < 4; ++ct) {
      const half8_t bf = *(const half8_t*)&Bs[ct * 16 + row16][quad * 8 + kt * 32];
      acc[ct] = __builtin_amdgcn_mfma_f32_16x16x32_f16(af, bf, acc[ct], 0, 0, 0);
    }
  }

#pragma unroll
  for (int ct = 0; ct < 4; ++ct) {
    const int nn = nbase + ct * 16 + row16;     // C col = lane&15
    const float bias = b_ih[nn] + b_hh[nn];
#pragma unroll
    for (int r = 0; r < 4; ++r) {
      const int bb = wave * 16 + quad * 4 + r;  // C row = quad*4 + reg
      U[((size_t)t * BB + bb) * HH + nn] = (_Float16)(acc[ct][r] + bias);
    }
  }
}

// ---------------------------------------------------------------------------
// Part B: recurrence — R13 hybrid MFMA(3 tiles) + v_dot2(1 tile).
//   R10-R12 post-mortem: allocator parks weight regs beyond ~130 arch VGPRs
//   (AGPR shuttle per use) regardless of pins/waves_per_eu; and 8-wave
//   variants are DS-pipe-bound on broadcast reads. Abandon pure-VALU.
//   Hybrid exploits m114 (MFMA and VALU pipes overlap fully):
//     * tiles 0..2 (48 cols/wave): MFMA from AGPR "+a" (R9-proven) ->
//       24 MFMA/wave = 466 cy/SIMD issue (was 620).
//     * tile 3 (16 cols/wave): lane (q=l>>4, r=l&15) owns col 64w+48+r over
//       k-set {32c+8q+j} — exactly the k-values its ha[c] A-fragments hold,
//       so the dot half needs ZERO extra LDS reads. Weights = 8 half8 = 32
//       VGPRs (under the allocator comfort zone; worst-case park = 32
//       shuttles/step, hidden under the 466-cy MFMA issue).
//     * q-reduction: __shfl_xor 16 then 32 (+adds); all 4 q-lanes of a col
//       get the sum; quad==3 lanes finalize it -> every lane still
//       finalizes n = tid. Finalize/u-stream/hbuf identical to R9.
//   Predicted step ~466+280 = ~745 cy (was 942).
// ---------------------------------------------------------------------------
__global__ __launch_bounds__(256)
__attribute__((amdgpu_waves_per_eu(1, 1)))
void rnn_scan_kernel(
    const _Float16* __restrict__ U, const _Float16* __restrict__ WhhT,
    float* __restrict__ out) {
  const int b = blockIdx.x;
  const int tid = threadIdx.x;
  const int w = tid >> 6;
  const int l = tid & 63;
  const int col = l & 15;    // n within tile
  const int quad = l >> 4;   // MFMA quad / k-group for the dot tile

  __shared__ __align__(16) _Float16 hbuf[2][HH];  // 1 KB ping-pong

  // MFMA B-frags for n-tiles 0..2: wb[tt][c] as in R9, pinned to AGPR.
  half8_t wb[3][8];
#pragma unroll
  for (int tt = 0; tt < 3; ++tt) {
    const _Float16* base = WhhT + (size_t)(64 * w + 16 * tt + col) * HH + quad * 8;
#pragma unroll
    for (int c = 0; c < 8; ++c) wb[tt][c] = *(const half8_t*)(base + 32 * c);
  }
  asm volatile("" : "+a"(wb[0][0]), "+a"(wb[0][1]), "+a"(wb[0][2]), "+a"(wb[0][3]),
                    "+a"(wb[0][4]), "+a"(wb[0][5]), "+a"(wb[0][6]), "+a"(wb[0][7]),
                    "+a"(wb[1][0]), "+a"(wb[1][1]), "+a"(wb[1][2]), "+a"(wb[1][3]),
                    "+a"(wb[1][4]), "+a"(wb[1][5]), "+a"(wb[1][6]), "+a"(wb[1][7]));
  asm volatile("" : "+a"(wb[2][0]), "+a"(wb[2][1]), "+a"(wb[2][2]), "+a"(wb[2][3]),
                    "+a"(wb[2][4]), "+a"(wb[2][5]), "+a"(wb[2][6]), "+a"(wb[2][7]));

  // dot weights for n-tile 3: wd[c] = WhhT[64w+48+col][32c+8q .. +8]
  // (matches ha[c]'s k-coverage; 16B-aligned: byte off = 64c + 16q).
  half8_t wd[8];
  {
    const _Float16* dbase = WhhT + (size_t)(64 * w + 48 + col) * HH + quad * 8;
#pragma unroll
    for (int c = 0; c < 8; ++c) wd[c] = *(const half8_t*)(dbase + 32 * c);
  }
  asm volatile("" : "+v"(wd[0]), "+v"(wd[1]), "+v"(wd[2]), "+v"(wd[3]),
                    "+v"(wd[4]), "+v"(wd[5]), "+v"(wd[6]), "+v"(wd[7]));

  hbuf[0][tid] = (_Float16)0.f;  // h0 = 0

  // Thread tid finalizes output n = tid: u stream is per-thread contiguous.
  const _Float16* Up = U + b * HH + tid;  // step stride = BB*HH halfs
  _Float16 uc[8], un[8];
#pragma unroll
  for (int s = 0; s < 8; ++s) uc[s] = Up[(size_t)s * (BB * HH)];

  float hn = 0.f;
  __syncthreads();

  for (int tc = 0; tc < TT; tc += 8) {
    // Issue all next-chunk u-loads; only the first barrier after drains them.
    const int tn = (tc + 8) & (TT - 1);
#pragma unroll
    for (int s = 0; s < 8; ++s) un[s] = Up[(size_t)(tn + s) * (BB * HH)];

#pragma unroll
    for (int s = 0; s < 8; ++s) {
      const int t = tc + s;

      // ---- A-frags: broadcast h chunks; lanes of a quad read same 16B ----
      const _Float16* hrow = hbuf[t & 1] + quad * 8;
      half8_t ha[8];
#pragma unroll
      for (int c = 0; c < 8; ++c) ha[c] = *(const half8_t*)(hrow + 32 * c);
      // Batch: all 8 reads issue first, ONE lgkmcnt wait.
      asm volatile("" : "+v"(ha[0]), "+v"(ha[1]), "+v"(ha[2]), "+v"(ha[3]),
                        "+v"(ha[4]), "+v"(ha[5]), "+v"(ha[6]), "+v"(ha[7]));

      // ---- dot tile (issues on VALU, overlaps the MFMA pipe) ----
      float d0 = 0.f, d1 = 0.f, d2 = 0.f, d3 = 0.f;
#pragma unroll
      for (int c = 0; c < 8; ++c) {
        const half2_t h0 = {ha[c][0], ha[c][1]}, w0 = {wd[c][0], wd[c][1]};
        const half2_t h1 = {ha[c][2], ha[c][3]}, w1 = {wd[c][2], wd[c][3]};
        const half2_t h2 = {ha[c][4], ha[c][5]}, w2 = {wd[c][4], wd[c][5]};
        const half2_t h3 = {ha[c][6], ha[c][7]}, w3 = {wd[c][6], wd[c][7]};
        d0 = fdot2(h0, w0, d0);   // 4 independent chains of 8
        d1 = fdot2(h1, w1, d1);
        d2 = fdot2(h2, w2, d2);
        d3 = fdot2(h3, w3, d3);
      }
      float dsum = (d0 + d1) + (d2 + d3);
      // reduce over the 4 q-lanes of this col (l^16, l^32)
      dsum += __shfl_xor(dsum, 16, 64);
      dsum += __shfl_xor(dsum, 32, 64);

      // ---- 24 MFMAs: 3 independent k-chains (tiles 0..2) ----
      f32x4 cacc[3];
#pragma unroll
      for (int tt = 0; tt < 3; ++tt) cacc[tt] = (f32x4){0.f, 0.f, 0.f, 0.f};
#pragma unroll
      for (int c = 0; c < 8; ++c)
#pragma unroll
        for (int tt = 0; tt < 3; ++tt)
          cacc[tt] = __builtin_amdgcn_mfma_f32_16x16x32_f16(ha[c], wb[tt][c], cacc[tt], 0, 0, 0);

      // ---- finalize: quad q owns tile q; tile 3 comes from the dot ----
      float y = cacc[0][0];
      y = (quad == 1) ? cacc[1][0] : y;
      y = (quad == 2) ? cacc[2][0] : y;
      y = (quad == 3) ? dsum : y;

      const float a = (float)uc[s] + y;
      // tanh(a) = 1 - 2/(exp(2a)+1)
      const float e = __builtin_amdgcn_exp2f(a * 2.885390081777927f);  // 2*log2(e)
      hn = 1.f - 2.f * __builtin_amdgcn_rcpf(e + 1.f);
      hbuf[(t + 1) & 1][tid] = (_Float16)hn;

      // Raw barrier: drain own LDS/shfl ops only; u prefetch stays in flight.
      asm volatile("s_waitcnt lgkmcnt(0)\n\ts_barrier" ::: "memory");
    }
#pragma unroll
    for (int s = 0; s < 8; ++s) uc[s] = un[s];
  }
  out[(size_t)b * HH + tid] = hn;
}

// ---------------------------------------------------------------------------
extern "C" void kernel_launch(void* const* d_in, const int* in_sizes, int n_in,
                              void* d_out, int out_size, void* d_ws, size_t ws_size,
                              hipStream_t stream) {
  const int*   source = (const int*)d_in[0];
  const float* emb    = (const float*)d_in[1];
  const float* Wih    = (const float*)d_in[2];
  const float* Whh    = (const float*)d_in[3];
  const float* bih    = (const float*)d_in[4];
  const float* bhh    = (const float*)d_in[5];
  float* out = (float*)d_out;

  char* ws = (char*)d_ws;
  _Float16* U    = (_Float16*)ws;                    // 2048*64*256*2 = 67,108,864 B
  _Float16* WihT = (_Float16*)(ws + 67108864);       // 131,072 B
  _Float16* WhhT = (_Float16*)(ws + 67239936);       // 131,072 B (total ~67.4 MB)

  prep_kernel<<<dim3(256), dim3(256), 0, stream>>>(Wih, Whh, WihT, WhhT);
  embed_gemm_kernel<<<dim3(TT, 4), dim3(256), 0, stream>>>(source, emb, WihT, bih, bhh, U);
  rnn_scan_kernel<<<dim3(BB), dim3(256), 0, stream>>>(U, WhhT, out);
}

// Round 5
// 978.419 us; speedup vs baseline: 1.2569x; 1.2470x over previous
//
#include <hip/hip_runtime.h>

#define TT 2048
#define BB 64
#define HH 256   // EMB == HID == 256

typedef _Float16 half2_t __attribute__((ext_vector_type(2)));
typedef _Float16 half8_t __attribute__((ext_vector_type(8)));
typedef float f32x4 __attribute__((ext_vector_type(4)));

// ---------------------------------------------------------------------------
// prep: transpose + fp16-convert W_ih and W_hh into [N][K] row-major.
// ---------------------------------------------------------------------------
__global__ void prep_kernel(const float* __restrict__ Wih, const float* __restrict__ Whh,
                            _Float16* __restrict__ WihT, _Float16* __restrict__ WhhT) {
  const int n = blockIdx.x;   // output column
  const int k = threadIdx.x;  // input row
  WihT[n * HH + k] = (_Float16)Wih[k * HH + n];
  WhhT[n * HH + k] = (_Float16)Whh[k * HH + n];
}

// ---------------------------------------------------------------------------
// Part A: U[t][b][n] = (emb[source[b][t]] @ W_ih)[n] + b_ih[n] + b_hh[n], fp16.
// (unchanged — verified correct; scan dominates runtime)
// ---------------------------------------------------------------------------
__global__ __launch_bounds__(256, 2) void embed_gemm_kernel(
    const int* __restrict__ source, const float* __restrict__ emb,
    const _Float16* __restrict__ WihT, const float* __restrict__ b_ih,
    const float* __restrict__ b_hh, _Float16* __restrict__ U) {
  const int t = blockIdx.x;
  const int nbase = blockIdx.y * 64;
  __shared__ __align__(16) _Float16 Bs[64][280];

  const int tid = threadIdx.x;
  for (int c = tid; c < 64 * 32; c += 256) {
    const int n = c >> 5;
    const int ko = (c & 31) * 8;
    *(half8_t*)&Bs[n][ko] = *(const half8_t*)(WihT + (size_t)(nbase + n) * HH + ko);
  }
  __syncthreads();

  const int lane = tid & 63;
  const int wave = tid >> 6;
  const int row16 = lane & 15;
  const int quad = lane >> 4;
  const int b = wave * 16 + row16;              // A-fragment row = batch
  const int src = source[b * TT + t];           // source is [B][T]
  const float* arow = emb + (size_t)src * HH + quad * 8;

  f32x4 acc[4];
#pragma unroll
  for (int ct = 0; ct < 4; ++ct) acc[ct] = (f32x4){0.f, 0.f, 0.f, 0.f};

#pragma unroll
  for (int kt = 0; kt < 8; ++kt) {
    const float4 x0 = *(const float4*)(arow + kt * 32);
    const float4 x1 = *(const float4*)(arow + kt * 32 + 4);
    half8_t af;
    af[0] = (_Float16)x0.x; af[1] = (_Float16)x0.y;
    af[2] = (_Float16)x0.z; af[3] = (_Float16)x0.w;
    af[4] = (_Float16)x1.x; af[5] = (_Float16)x1.y;
    af[6] = (_Float16)x1.z; af[7] = (_Float16)x1.w;
#pragma unroll
    for (int ct = 0; ct < 4; ++ct) {
      const half8_t bf = *(const half8_t*)&Bs[ct * 16 + row16][quad * 8 + kt * 32];
      acc[ct] = __builtin_amdgcn_mfma_f32_16x16x32_f16(af, bf, acc[ct], 0, 0, 0);
    }
  }

#pragma unroll
  for (int ct = 0; ct < 4; ++ct) {
    const int nn = nbase + ct * 16 + row16;     // C col = lane&15
    const float bias = b_ih[nn] + b_hh[nn];
#pragma unroll
    for (int r = 0; r < 4; ++r) {
      const int bb = wave * 16 + quad * 4 + r;  // C row = quad*4 + reg
      U[((size_t)t * BB + bb) * HH + nn] = (_Float16)(acc[ct][r] + bias);
    }
  }
}

// ---------------------------------------------------------------------------
// Part B: recurrence — R14: 8 waves (2/SIMD), n-split, MFMA from AGPR.
//   R13 post-mortem: within-wave MFMA+VALU do NOT overlap (m114's overlap is
//   across waves); the dot tile + 2 cross-lane shuffles ADDED ~300 cy serial.
//   Consolidated model: per-SIMD matrix-pipe time for the matvec is invariant
//   (~620 cy = 32 MFMA x 19.4 cy regardless of wave split). R9's remaining
//   ~320 cy/step is the exposed serial tail (h-read latency, finalize, tanh,
//   barrier) at 1 wave/SIMD. Fix: 8 waves, 2/SIMD — wave w owns n-cols
//   [32w, 32w+32) (2 tiles, 16 MFMA/step, 64 AGPR weights "+a" = proven
//   allocator regime; ~154 total regs < 256 budget). Each wave's tail hides
//   under the co-resident wave's MFMA issue. Per-n arithmetic IDENTICAL to
//   R9 (same fragments, same k-order) -> absmax should repeat exactly.
//   Predicted step ~680-740 cy (was 942).
// ---------------------------------------------------------------------------
__global__ __launch_bounds__(512)
__attribute__((amdgpu_waves_per_eu(2, 2)))
void rnn_scan_kernel(
    const _Float16* __restrict__ U, const _Float16* __restrict__ WhhT,
    float* __restrict__ out) {
  const int b = blockIdx.x;
  const int tid = threadIdx.x;   // 0..511
  const int w = tid >> 6;        // wave 0..7: owns n in [32w, 32w+32)
  const int l = tid & 63;
  const int col = l & 15;    // n within 16-tile
  const int quad = l >> 4;   // MFMA quad (k-group for A/B frags)

  __shared__ __align__(16) _Float16 hbuf[2][HH];  // 1 KB ping-pong

  // B-frags for this wave's 2 n-tiles: wb[tt][c] = WhhT[32w+16tt+col][32c+8q..+8]
  half8_t wb[2][8];
#pragma unroll
  for (int tt = 0; tt < 2; ++tt) {
    const _Float16* base = WhhT + (size_t)(32 * w + 16 * tt + col) * HH + quad * 8;
#pragma unroll
    for (int c = 0; c < 8; ++c) wb[tt][c] = *(const half8_t*)(base + 32 * c);
  }
  // Pin into AGPRs: one-time v_accvgpr_write; MFMA reads B from AGPR natively.
  asm volatile("" : "+a"(wb[0][0]), "+a"(wb[0][1]), "+a"(wb[0][2]), "+a"(wb[0][3]),
                    "+a"(wb[0][4]), "+a"(wb[0][5]), "+a"(wb[0][6]), "+a"(wb[0][7]),
                    "+a"(wb[1][0]), "+a"(wb[1][1]), "+a"(wb[1][2]), "+a"(wb[1][3]),
                    "+a"(wb[1][4]), "+a"(wb[1][5]), "+a"(wb[1][6]), "+a"(wb[1][7]));

  if (tid < HH) hbuf[0][tid] = (_Float16)0.f;  // h0 = 0

  // Finalized output: n = 32w + 16*(quad&1) + col. Quads 0,1 are the real
  // finalizers; quads 2,3 compute duplicates (uniform code, no divergence in
  // the hot loop) and are masked at the hbuf/out writes.
  const int nfin = 32 * w + 16 * (quad & 1) + col;
  const _Float16* Up = U + (size_t)b * HH + nfin;  // step stride = BB*HH halfs
  _Float16 uc[8], un[8];
#pragma unroll
  for (int s = 0; s < 8; ++s) uc[s] = Up[(size_t)s * (BB * HH)];

  float hn = 0.f;
  __syncthreads();  // once, outside the loop (vmcnt drain here is harmless)

  for (int tc = 0; tc < TT; tc += 8) {
    // Issue next-chunk u-loads; raw barriers below never drain vmcnt, so
    // these stay in flight until the uc=un copy (8 steps of slack).
    const int tn = (tc + 8) & (TT - 1);
#pragma unroll
    for (int s = 0; s < 8; ++s) un[s] = Up[(size_t)(tn + s) * (BB * HH)];

#pragma unroll
    for (int s = 0; s < 8; ++s) {
      const int t = tc + s;

      // ---- A-frags: broadcast h chunks; lanes of a quad read same 16B ----
      const _Float16* hrow = hbuf[t & 1] + quad * 8;
      half8_t ha[8];
#pragma unroll
      for (int c = 0; c < 8; ++c) ha[c] = *(const half8_t*)(hrow + 32 * c);
      // Batch: all 8 reads issue first, ONE lgkmcnt wait.
      asm volatile("" : "+v"(ha[0]), "+v"(ha[1]), "+v"(ha[2]), "+v"(ha[3]),
                        "+v"(ha[4]), "+v"(ha[5]), "+v"(ha[6]), "+v"(ha[7]));

      // ---- 16 MFMAs: 2 independent k-chains (one per n-tile) ----
      f32x4 cacc[2];
      cacc[0] = (f32x4){0.f, 0.f, 0.f, 0.f};
      cacc[1] = (f32x4){0.f, 0.f, 0.f, 0.f};
#pragma unroll
      for (int c = 0; c < 8; ++c) {
        cacc[0] = __builtin_amdgcn_mfma_f32_16x16x32_f16(ha[c], wb[0][c], cacc[0], 0, 0, 0);
        cacc[1] = __builtin_amdgcn_mfma_f32_16x16x32_f16(ha[c], wb[1][c], cacc[1], 0, 0, 0);
      }

      // ---- finalize: quads 0,2 -> tile 0; quads 1,3 -> tile 1 ----
      const float y = (quad & 1) ? cacc[1][0] : cacc[0][0];
      const float a = (float)uc[s] + y;
      // tanh(a) = 1 - 2/(exp(2a)+1)
      const float e = __builtin_amdgcn_exp2f(a * 2.885390081777927f);  // 2*log2(e)
      hn = 1.f - 2.f * __builtin_amdgcn_rcpf(e + 1.f);
      if (quad < 2) hbuf[(t + 1) & 1][nfin] = (_Float16)hn;

      // ONE raw barrier/step: drain own LDS ops only; vmcnt untouched.
      asm volatile("s_waitcnt lgkmcnt(0)\n\ts_barrier" ::: "memory");
    }
#pragma unroll
    for (int s = 0; s < 8; ++s) uc[s] = un[s];
  }
  if (quad < 2) out[(size_t)b * HH + nfin] = hn;
}

// ---------------------------------------------------------------------------
extern "C" void kernel_launch(void* const* d_in, const int* in_sizes, int n_in,
                              void* d_out, int out_size, void* d_ws, size_t ws_size,
                              hipStream_t stream) {
  const int*   source = (const int*)d_in[0];
  const float* emb    = (const float*)d_in[1];
  const float* Wih    = (const float*)d_in[2];
  const float* Whh    = (const float*)d_in[3];
  const float* bih    = (const float*)d_in[4];
  const float* bhh    = (const float*)d_in[5];
  float* out = (float*)d_out;

  char* ws = (char*)d_ws;
  _Float16* U    = (_Float16*)ws;                    // 2048*64*256*2 = 67,108,864 B
  _Float16* WihT = (_Float16*)(ws + 67108864);       // 131,072 B
  _Float16* WhhT = (_Float16*)(ws + 67239936);       // 131,072 B (total ~67.4 MB)

  prep_kernel<<<dim3(256), dim3(256), 0, stream>>>(Wih, Whh, WihT, WhhT);
  embed_gemm_kernel<<<dim3(TT, 4), dim3(256), 0, stream>>>(source, emb, WihT, bih, bhh, U);
  rnn_scan_kernel<<<dim3(BB), dim3(512), 0, stream>>>(U, WhhT, out);
}

// Round 6
// 914.306 us; speedup vs baseline: 1.3450x; 1.0701x over previous
//
#include <hip/hip_runtime.h>

#define TT 2048
#define BB 64
#define HH 256   // EMB == HID == 256

typedef _Float16 half2_t __attribute__((ext_vector_type(2)));
typedef _Float16 half8_t __attribute__((ext_vector_type(8)));
typedef float f32x4 __attribute__((ext_vector_type(4)));

// ---------------------------------------------------------------------------
// prep: transpose + fp16-convert W_ih and W_hh into [N][K] row-major.
// ---------------------------------------------------------------------------
__global__ void prep_kernel(const float* __restrict__ Wih, const float* __restrict__ Whh,
                            _Float16* __restrict__ WihT, _Float16* __restrict__ WhhT) {
  const int n = blockIdx.x;   // output column
  const int k = threadIdx.x;  // input row
  WihT[n * HH + k] = (_Float16)Wih[k * HH + n];
  WhhT[n * HH + k] = (_Float16)Whh[k * HH + n];
}

// ---------------------------------------------------------------------------
// Part A: U[t][b][n] = (emb[source[b][t]] @ W_ih)[n] + b_ih[n] + b_hh[n], fp16.
// (unchanged — verified correct; scan dominates runtime)
// ---------------------------------------------------------------------------
__global__ __launch_bounds__(256, 2) void embed_gemm_kernel(
    const int* __restrict__ source, const float* __restrict__ emb,
    const _Float16* __restrict__ WihT, const float* __restrict__ b_ih,
    const float* __restrict__ b_hh, _Float16* __restrict__ U) {
  const int t = blockIdx.x;
  const int nbase = blockIdx.y * 64;
  __shared__ __align__(16) _Float16 Bs[64][280];

  const int tid = threadIdx.x;
  for (int c = tid; c < 64 * 32; c += 256) {
    const int n = c >> 5;
    const int ko = (c & 31) * 8;
    *(half8_t*)&Bs[n][ko] = *(const half8_t*)(WihT + (size_t)(nbase + n) * HH + ko);
  }
  __syncthreads();

  const int lane = tid & 63;
  const int wave = tid >> 6;
  const int row16 = lane & 15;
  const int quad = lane >> 4;
  const int b = wave * 16 + row16;              // A-fragment row = batch
  const int src = source[b * TT + t];           // source is [B][T]
  const float* arow = emb + (size_t)src * HH + quad * 8;

  f32x4 acc[4];
#pragma unroll
  for (int ct = 0; ct < 4; ++ct) acc[ct] = (f32x4){0.f, 0.f, 0.f, 0.f};

#pragma unroll
  for (int kt = 0; kt < 8; ++kt) {
    const float4 x0 = *(const float4*)(arow + kt * 32);
    const float4 x1 = *(const float4*)(arow + kt * 32 + 4);
    half8_t af;
    af[0] = (_Float16)x0.x; af[1] = (_Float16)x0.y;
    af[2] = (_Float16)x0.z; af[3] = (_Float16)x0.w;
    af[4] = (_Float16)x1.x; af[5] = (_Float16)x1.y;
    af[6] = (_Float16)x1.z; af[7] = (_Float16)x1.w;
#pragma unroll
    for (int ct = 0; ct < 4; ++ct) {
      const half8_t bf = *(const half8_t*)&Bs[ct * 16 + row16][quad * 8 + kt * 32];
      acc[ct] = __builtin_amdgcn_mfma_f32_16x16x32_f16(af, bf, acc[ct], 0, 0, 0);
    }
  }

#pragma unroll
  for (int ct = 0; ct < 4; ++ct) {
    const int nn = nbase + ct * 16 + row16;     // C col = lane&15
    const float bias = b_ih[nn] + b_hh[nn];
#pragma unroll
    for (int r = 0; r < 4; ++r) {
      const int bb = wave * 16 + quad * 4 + r;  // C row = quad*4 + reg
      U[((size_t)t * BB + bb) * HH + nn] = (_Float16)(acc[ct][r] + bias);
    }
  }
}

// ---------------------------------------------------------------------------
// Part B: recurrence — R15: R9 structure + cross-barrier own-chunk pre-issue.
//   R14 post-mortem: 2 waves/SIMD with one all-wave barrier runs in lockstep
//   (ds-latency + MFMA bursts + tails collide, not interleave) -> no hiding.
//   Model (6 rounds): per-CU MFMA issue 620 cy/step is a hard floor (matvec
//   MFMA useful fraction = 1/16 structurally); R9's remaining 322 cy is the
//   exposed tail. R15 attacks the tail INTRA-wave:
//     * wave w's h-slice [64w,64w+64) = k-chunks {2w, 2w+1}, written by its
//       OWN lanes. Same-wave DS instr ordering => after writing h_{t+1} the
//       wave reads those 2 chunks and issues 8 MFMAs of step t+1 BEFORE the
//       barrier. That 155-cy matrix-pipe backlog drains during the barrier
//       wait + post-barrier ds_read latency -> matrix pipe never idles
//       across the step boundary.
//     * register-index discipline: wb[tt][j] holds chunk c=(2w+j)&7 so own
//       chunks are STATIC indices 0,1 (runtime addresses, static reg idx).
//       Accumulation order rotates per wave (f32 reassociation only).
//   Predicted step ~790-820 cy (was 942).
// ---------------------------------------------------------------------------
__global__ __launch_bounds__(256)
__attribute__((amdgpu_waves_per_eu(1, 1)))
void rnn_scan_kernel(
    const _Float16* __restrict__ U, const _Float16* __restrict__ WhhT,
    float* __restrict__ out) {
  const int b = blockIdx.x;
  const int tid = threadIdx.x;
  const int w = tid >> 6;
  const int l = tid & 63;
  const int col = l & 15;    // n within tile
  const int quad = l >> 4;   // MFMA quad

  __shared__ __align__(16) _Float16 hbuf[2][HH];  // 1 KB ping-pong

  // wb[tt][j]: B-frag for n-tile 64w+16tt, k-chunk c=(2w+j)&7 (own chunks at
  // j=0,1). Lane reads WhhT[(64w+16tt+col)][32c + quad*8 .. +8] (16B aligned).
  half8_t wb[4][8];
#pragma unroll
  for (int tt = 0; tt < 4; ++tt) {
    const _Float16* base = WhhT + (size_t)(64 * w + 16 * tt + col) * HH + quad * 8;
#pragma unroll
    for (int j = 0; j < 8; ++j) {
      const int c = (2 * w + j) & 7;
      wb[tt][j] = *(const half8_t*)(base + 32 * c);
    }
  }
  // Pin into AGPRs ("a"): one-time v_accvgpr_write; MFMA reads B from AGPR.
  asm volatile("" : "+a"(wb[0][0]), "+a"(wb[0][1]), "+a"(wb[0][2]), "+a"(wb[0][3]),
                    "+a"(wb[0][4]), "+a"(wb[0][5]), "+a"(wb[0][6]), "+a"(wb[0][7]),
                    "+a"(wb[1][0]), "+a"(wb[1][1]), "+a"(wb[1][2]), "+a"(wb[1][3]),
                    "+a"(wb[1][4]), "+a"(wb[1][5]), "+a"(wb[1][6]), "+a"(wb[1][7]));
  asm volatile("" : "+a"(wb[2][0]), "+a"(wb[2][1]), "+a"(wb[2][2]), "+a"(wb[2][3]),
                    "+a"(wb[2][4]), "+a"(wb[2][5]), "+a"(wb[2][6]), "+a"(wb[2][7]),
                    "+a"(wb[3][0]), "+a"(wb[3][1]), "+a"(wb[3][2]), "+a"(wb[3][3]),
                    "+a"(wb[3][4]), "+a"(wb[3][5]), "+a"(wb[3][6]), "+a"(wb[3][7]));

  // h-read offsets (halfs): chunk (2w+j)&7 at 32*c + 8*quad.
  const int oO0 = 32 * ((2 * w + 0) & 7) + 8 * quad;  // own chunk j=0
  const int oO1 = 32 * ((2 * w + 1) & 7) + 8 * quad;  // own chunk j=1
  const int oX2 = 32 * ((2 * w + 2) & 7) + 8 * quad;
  const int oX3 = 32 * ((2 * w + 3) & 7) + 8 * quad;
  const int oX4 = 32 * ((2 * w + 4) & 7) + 8 * quad;
  const int oX5 = 32 * ((2 * w + 5) & 7) + 8 * quad;
  const int oX6 = 32 * ((2 * w + 6) & 7) + 8 * quad;
  const int oX7 = 32 * ((2 * w + 7) & 7) + 8 * quad;

  hbuf[0][tid] = (_Float16)0.f;  // h0 = 0

  // Thread tid finalizes output n = tid: u stream is per-thread contiguous.
  const _Float16* Up = U + b * HH + tid;  // step stride = BB*HH halfs
  _Float16 uc[8], un[8];
#pragma unroll
  for (int s = 0; s < 8; ++s) uc[s] = Up[(size_t)s * (BB * HH)];

  float hn = 0.f;
  f32x4 cacc[4];
#pragma unroll
  for (int tt = 0; tt < 4; ++tt) cacc[tt] = (f32x4){0.f, 0.f, 0.f, 0.f};

  // ---- prologue: own-chunk frags of h_0 + 8 pre-issued MFMAs (step 0) ----
  {
    half8_t hoA = *(const half8_t*)(hbuf[0] + oO0);
    half8_t hoB = *(const half8_t*)(hbuf[0] + oO1);
    asm volatile("" : "+v"(hoA), "+v"(hoB));
#pragma unroll
    for (int tt = 0; tt < 4; ++tt)
      cacc[tt] = __builtin_amdgcn_mfma_f32_16x16x32_f16(hoA, wb[tt][0], cacc[tt], 0, 0, 0);
#pragma unroll
    for (int tt = 0; tt < 4; ++tt)
      cacc[tt] = __builtin_amdgcn_mfma_f32_16x16x32_f16(hoB, wb[tt][1], cacc[tt], 0, 0, 0);
  }

  for (int tc = 0; tc < TT; tc += 8) {
    // Issue all next-chunk u-loads; raw barriers never drain vmcnt, so they
    // stay in flight until the uc=un copy (8 steps of slack).
    const int tn = (tc + 8) & (TT - 1);
#pragma unroll
    for (int s = 0; s < 8; ++s) un[s] = Up[(size_t)(tn + s) * (BB * HH)];

#pragma unroll
    for (int s = 0; s < 8; ++s) {
      const int t = tc + s;

      // Top barrier: h_t cross-wave writes visible. Pre-issued MFMAs from
      // the previous iteration drain in the matrix pipe during the wait.
      asm volatile("s_waitcnt lgkmcnt(0)\n\ts_barrier" ::: "memory");

      // ---- 6 cross-wave chunks of h_t (broadcast b128 reads) ----
      const _Float16* hb = hbuf[t & 1];
      half8_t h2 = *(const half8_t*)(hb + oX2);
      half8_t h3 = *(const half8_t*)(hb + oX3);
      half8_t h4 = *(const half8_t*)(hb + oX4);
      half8_t h5 = *(const half8_t*)(hb + oX5);
      half8_t h6 = *(const half8_t*)(hb + oX6);
      half8_t h7 = *(const half8_t*)(hb + oX7);
      asm volatile("" : "+v"(h2), "+v"(h3), "+v"(h4), "+v"(h5), "+v"(h6), "+v"(h7));

      // ---- 24 MFMAs completing step t (4 chains, chunk-major) ----
#pragma unroll
      for (int tt = 0; tt < 4; ++tt)
        cacc[tt] = __builtin_amdgcn_mfma_f32_16x16x32_f16(h2, wb[tt][2], cacc[tt], 0, 0, 0);
#pragma unroll
      for (int tt = 0; tt < 4; ++tt)
        cacc[tt] = __builtin_amdgcn_mfma_f32_16x16x32_f16(h3, wb[tt][3], cacc[tt], 0, 0, 0);
#pragma unroll
      for (int tt = 0; tt < 4; ++tt)
        cacc[tt] = __builtin_amdgcn_mfma_f32_16x16x32_f16(h4, wb[tt][4], cacc[tt], 0, 0, 0);
#pragma unroll
      for (int tt = 0; tt < 4; ++tt)
        cacc[tt] = __builtin_amdgcn_mfma_f32_16x16x32_f16(h5, wb[tt][5], cacc[tt], 0, 0, 0);
#pragma unroll
      for (int tt = 0; tt < 4; ++tt)
        cacc[tt] = __builtin_amdgcn_mfma_f32_16x16x32_f16(h6, wb[tt][6], cacc[tt], 0, 0, 0);
#pragma unroll
      for (int tt = 0; tt < 4; ++tt)
        cacc[tt] = __builtin_amdgcn_mfma_f32_16x16x32_f16(h7, wb[tt][7], cacc[tt], 0, 0, 0);

      // ---- finalize: quad q owns tile q  =>  n = 64w + 16q + col = tid ----
      float y = cacc[0][0];
      y = (quad == 1) ? cacc[1][0] : y;
      y = (quad == 2) ? cacc[2][0] : y;
      y = (quad == 3) ? cacc[3][0] : y;

      const float a = (float)uc[s] + y;
      // tanh(a) = 1 - 2/(exp(2a)+1)
      const float e = __builtin_amdgcn_exp2f(a * 2.885390081777927f);  // 2*log2(e)
      hn = 1.f - 2.f * __builtin_amdgcn_rcpf(e + 1.f);

      // ---- write own h_{t+1}, read own chunks, pre-issue 8 MFMAs (t+1) ----
      _Float16* hb1 = (_Float16*)hbuf[(t + 1) & 1];
      hb1[tid] = (_Float16)hn;
      // Same-wave DS ordering: these reads see the wave's own writes above.
      half8_t hoA = *(const half8_t*)(hb1 + oO0);
      half8_t hoB = *(const half8_t*)(hb1 + oO1);
      asm volatile("" : "+v"(hoA), "+v"(hoB));
#pragma unroll
      for (int tt = 0; tt < 4; ++tt) cacc[tt] = (f32x4){0.f, 0.f, 0.f, 0.f};
#pragma unroll
      for (int tt = 0; tt < 4; ++tt)
        cacc[tt] = __builtin_amdgcn_mfma_f32_16x16x32_f16(hoA, wb[tt][0], cacc[tt], 0, 0, 0);
#pragma unroll
      for (int tt = 0; tt < 4; ++tt)
        cacc[tt] = __builtin_amdgcn_mfma_f32_16x16x32_f16(hoB, wb[tt][1], cacc[tt], 0, 0, 0);
      // loop wraps to lgkmcnt(0)+barrier; the 8 MFMAs drain across it.
    }
#pragma unroll
    for (int s = 0; s < 8; ++s) uc[s] = un[s];
  }
  out[(size_t)b * HH + tid] = hn;
}

// ---------------------------------------------------------------------------
extern "C" void kernel_launch(void* const* d_in, const int* in_sizes, int n_in,
                              void* d_out, int out_size, void* d_ws, size_t ws_size,
                              hipStream_t stream) {
  const int*   source = (const int*)d_in[0];
  const float* emb    = (const float*)d_in[1];
  const float* Wih    = (const float*)d_in[2];
  const float* Whh    = (const float*)d_in[3];
  const float* bih    = (const float*)d_in[4];
  const float* bhh    = (const float*)d_in[5];
  float* out = (float*)d_out;

  char* ws = (char*)d_ws;
  _Float16* U    = (_Float16*)ws;                    // 2048*64*256*2 = 67,108,864 B
  _Float16* WihT = (_Float16*)(ws + 67108864);       // 131,072 B
  _Float16* WhhT = (_Float16*)(ws + 67239936);       // 131,072 B (total ~67.4 MB)

  prep_kernel<<<dim3(256), dim3(256), 0, stream>>>(Wih, Whh, WihT, WhhT);
  embed_gemm_kernel<<<dim3(TT, 4), dim3(256), 0, stream>>>(source, emb, WihT, bih, bhh, U);
  rnn_scan_kernel<<<dim3(BB), dim3(256), 0, stream>>>(U, WhhT, out);
}